// Round 1
// baseline (8649.622 us; speedup 1.0000x reference)
//
#include <hip/hip_runtime.h>
#include <hip/hip_bf16.h>
#include <cstdint>
#include <cstddef>

#define N_NODES 20000
#define N_EDGES 640000
#define DDIM    256
#define HIDD    512
#define NBLK    6
#define HEXP    2048   // HID*EXP
#define NCLS    3
#define RNK     512
#define NGENE   6640
#define NBATCH  4096

__device__ __forceinline__ float gelu_tanh(float x) {
    float x3 = x * x * x;
    return 0.5f * x * (1.f + tanhf(0.7978845608028654f * (x + 0.044715f * x3)));
}

// ---------------- utility kernels ----------------
__global__ __launch_bounds__(256) void copy4_kernel(float4* __restrict__ dst,
                                                    const float4* __restrict__ src, int n4) {
    int i = blockIdx.x * 256 + threadIdx.x;
    if (i < n4) dst[i] = src[i];
}

__global__ __launch_bounds__(256) void zero4_kernel(float4* __restrict__ dst, int n4) {
    int i = blockIdx.x * 256 + threadIdx.x;
    if (i < n4) dst[i] = make_float4(0.f, 0.f, 0.f, 0.f);
}

// X += relu(AGG + bias)   (elementwise over N_NODES*DDIM, float4 granularity)
__global__ __launch_bounds__(256) void node_update_kernel(float* __restrict__ X,
                                                          const float* __restrict__ AGG,
                                                          const float* __restrict__ bias) {
    int i = blockIdx.x * 256 + threadIdx.x;
    const int n4 = N_NODES * DDIM / 4;
    if (i >= n4) return;
    float4 x = ((float4*)X)[i];
    float4 a = ((const float4*)AGG)[i];
    int c = (i * 4) & (DDIM - 1);
    x.x += fmaxf(a.x + bias[c + 0], 0.f);
    x.y += fmaxf(a.y + bias[c + 1], 0.f);
    x.z += fmaxf(a.z + bias[c + 2], 0.f);
    x.w += fmaxf(a.w + bias[c + 3], 0.f);
    ((float4*)X)[i] = x;
}

// one wave (64 lanes) per edge; each lane handles 4 channels
__global__ __launch_bounds__(256) void edge_scatter_kernel(const float* __restrict__ Y,
                                                           const int* __restrict__ src,
                                                           const int* __restrict__ dst,
                                                           const float* __restrict__ ew,
                                                           float* __restrict__ AGG) {
    long long gid = (long long)blockIdx.x * 256 + threadIdx.x;
    int e  = (int)(gid >> 6);
    int c4 = (int)(gid & 63) * 4;
    if (e >= N_EDGES) return;
    int s = src[e];
    int d = dst[e];
    float w = ew[e];
    float4 v = *(const float4*)(Y + (size_t)s * DDIM + c4);
    float* ap = AGG + (size_t)d * DDIM + c4;
    atomicAdd(ap + 0, v.x * w);
    atomicAdd(ap + 1, v.y * w);
    atomicAdd(ap + 2, v.z * w);
    atomicAdd(ap + 3, v.w * w);
}

// EMB[b][t] = idx[b] >= 0 ? Z[idx[b]][t] : oov[t]   (blockDim = DDIM)
__global__ __launch_bounds__(256) void gather_emb_kernel(const float* __restrict__ Z,
                                                         const int* __restrict__ idxs,
                                                         const float* __restrict__ oov,
                                                         float* __restrict__ EMB) {
    int b = blockIdx.x, t = threadIdx.x;
    int id = idxs[b];
    EMB[(size_t)b * DDIM + t] = (id >= 0) ? Z[(size_t)id * DDIM + t] : oov[t];
}

// one block (256 threads) per row; population variance, eps=1e-5
__global__ __launch_bounds__(256) void ln_kernel(const float* __restrict__ X,
                                                 const float* __restrict__ g,
                                                 const float* __restrict__ bb,
                                                 float* __restrict__ Y, int ncol) {
    __shared__ float s1[256];
    __shared__ float s2[256];
    int row = blockIdx.x, t = threadIdx.x;
    const float* x = X + (size_t)row * ncol;
    float sum = 0.f, sq = 0.f;
    for (int c = t; c < ncol; c += 256) {
        float v = x[c];
        sum += v;
        sq  += v * v;
    }
    s1[t] = sum; s2[t] = sq;
    __syncthreads();
    for (int off = 128; off > 0; off >>= 1) {
        if (t < off) { s1[t] += s1[t + off]; s2[t] += s2[t + off]; }
        __syncthreads();
    }
    float inv = 1.f / (float)ncol;
    float mu  = s1[0] * inv;
    float var = s2[0] * inv - mu * mu;
    float r   = rsqrtf(var + 1e-5f);
    float* y = Y + (size_t)row * ncol;
    for (int c = t; c < ncol; c += 256) {
        y[c] = (x[c] - mu) * r * g[c] + bb[c];
    }
}

// ---------------- generic f32 GEMM ----------------
// C[M,N] = epi(A[M,K] @ B + bias)
// tile 128x128, k-step 16, 256 threads, 8x8 micro-tile per thread
// BT=false: B is [K,N] row-major (ldb = row stride)
// BT=true : B is [N,K] row-major (ldb = row stride), used as B^T
// EPI: 0 = x+bias ; 2 = gelu(x+bias) ; 3 = C += x+bias (residual in-place)
template <int EPI, bool BT>
__global__ __launch_bounds__(256) void gemm_f32(const float* __restrict__ A, int lda,
                                                const float* __restrict__ Bm, int ldb,
                                                float* __restrict__ C, int ldc,
                                                const float* __restrict__ bias,
                                                int M, int N, int K) {
    __shared__ float As[16][132];
    __shared__ float Bs[16][132];
    const int tid = threadIdx.x;
    const int m0 = blockIdx.y * 128, n0 = blockIdx.x * 128;
    const int tx = tid & 15, ty = tid >> 4;

    float acc[8][8];
#pragma unroll
    for (int i = 0; i < 8; ++i)
#pragma unroll
        for (int j = 0; j < 8; ++j) acc[i][j] = 0.f;

    const int am = tid >> 1;        // 0..127 (A row within tile)
    const int ak = (tid & 1) * 8;   // 0/8    (A k-offset)
    const int bk = tid >> 4;        // 0..15  (B k row, BT=false)
    const int bn = (tid & 15) * 8;  // 0..120 (B n-offset, BT=false)
    const int tn = tid >> 1;        // 0..127 (B n row, BT=true)
    const int tk = (tid & 1) * 8;   // 0/8    (B k-offset, BT=true)

    for (int k0 = 0; k0 < K; k0 += 16) {
        // ---- stage A tile (transposed into As[k][m]) ----
        {
            float4 a0 = make_float4(0, 0, 0, 0), a1 = make_float4(0, 0, 0, 0);
            if (m0 + am < M) {
                const float* p = A + (size_t)(m0 + am) * lda + k0 + ak;
                a0 = *(const float4*)p;
                a1 = *(const float4*)(p + 4);
            }
            As[ak + 0][am] = a0.x; As[ak + 1][am] = a0.y;
            As[ak + 2][am] = a0.z; As[ak + 3][am] = a0.w;
            As[ak + 4][am] = a1.x; As[ak + 5][am] = a1.y;
            As[ak + 6][am] = a1.z; As[ak + 7][am] = a1.w;
        }
        // ---- stage B tile into Bs[k][n] ----
        if (!BT) {
            float4 b0 = make_float4(0, 0, 0, 0), b1 = make_float4(0, 0, 0, 0);
            const float* p = Bm + (size_t)(k0 + bk) * ldb + n0 + bn;
            if (n0 + bn < N)     b0 = *(const float4*)p;
            if (n0 + bn + 4 < N) b1 = *(const float4*)(p + 4);
            *(float4*)&Bs[bk][bn]     = b0;
            *(float4*)&Bs[bk][bn + 4] = b1;
        } else {
            float4 b0 = make_float4(0, 0, 0, 0), b1 = make_float4(0, 0, 0, 0);
            if (n0 + tn < N) {
                const float* p = Bm + (size_t)(n0 + tn) * ldb + k0 + tk;
                b0 = *(const float4*)p;
                b1 = *(const float4*)(p + 4);
            }
            Bs[tk + 0][tn] = b0.x; Bs[tk + 1][tn] = b0.y;
            Bs[tk + 2][tn] = b0.z; Bs[tk + 3][tn] = b0.w;
            Bs[tk + 4][tn] = b1.x; Bs[tk + 5][tn] = b1.y;
            Bs[tk + 6][tn] = b1.z; Bs[tk + 7][tn] = b1.w;
        }
        __syncthreads();
#pragma unroll
        for (int kk = 0; kk < 16; ++kk) {
            float4 a0 = *(const float4*)&As[kk][ty * 8];
            float4 a1 = *(const float4*)&As[kk][ty * 8 + 4];
            float4 b0 = *(const float4*)&Bs[kk][tx * 8];
            float4 b1 = *(const float4*)&Bs[kk][tx * 8 + 4];
            float av[8] = {a0.x, a0.y, a0.z, a0.w, a1.x, a1.y, a1.z, a1.w};
            float bv[8] = {b0.x, b0.y, b0.z, b0.w, b1.x, b1.y, b1.z, b1.w};
#pragma unroll
            for (int i = 0; i < 8; ++i)
#pragma unroll
                for (int j = 0; j < 8; ++j)
                    acc[i][j] = fmaf(av[i], bv[j], acc[i][j]);
        }
        __syncthreads();
    }

    // ---- epilogue ----
#pragma unroll
    for (int i = 0; i < 8; ++i) {
        int m = m0 + ty * 8 + i;
        if (m >= M) break;
#pragma unroll
        for (int j = 0; j < 8; ++j) {
            int n = n0 + tx * 8 + j;
            if (n >= N) continue;
            float v = acc[i][j] + (bias ? bias[n] : 0.f);
            if (EPI == 2) v = gelu_tanh(v);
            size_t off = (size_t)m * ldc + n;
            if (EPI == 3) v += C[off];
            C[off] = v;
        }
    }
}

// ---------------- launcher ----------------
extern "C" void kernel_launch(void* const* d_in, const int* in_sizes, int n_in,
                              void* d_out, int out_size, void* d_ws, size_t ws_size,
                              hipStream_t stream) {
    const int*   idxs = (const int*)d_in[0];
    const float* fro  = (const float*)d_in[1];
    const int*   eidx = (const int*)d_in[2];
    const float* ew   = (const float*)d_in[3];
    const float* W6   = (const float*)d_in[4];
    const float* b6   = (const float*)d_in[5];
    const float* W7   = (const float*)d_in[6];
    const float* b7   = (const float*)d_in[7];
    const float* Wp   = (const float*)d_in[8];
    const float* bp   = (const float*)d_in[9];
    const float* oov  = (const float*)d_in[10];
    const float* in_g = (const float*)d_in[11];
    const float* in_b = (const float*)d_in[12];
    const float* inW  = (const float*)d_in[13];
    const float* inb  = (const float*)d_in[14];
    const float* bg   = (const float*)d_in[15];
    const float* bb   = (const float*)d_in[16];
    const float* f1W  = (const float*)d_in[17];
    const float* f1b  = (const float*)d_in[18];
    const float* f2W  = (const float*)d_in[19];
    const float* f2b  = (const float*)d_in[20];
    const float* og   = (const float*)d_in[21];
    const float* ob   = (const float*)d_in[22];
    const float* oW   = (const float*)d_in[23];
    const float* obia = (const float*)d_in[24];
    const float* gene = (const float*)d_in[25];
    float* out = (float*)d_out;

    float* ws  = (float*)d_ws;
    float* X   = ws;                               // N_NODES*DDIM
    float* Y   = X   + (size_t)N_NODES * DDIM;     // N_NODES*DDIM
    float* AGG = Y   + (size_t)N_NODES * DDIM;     // N_NODES*DDIM
    float* EMB = AGG + (size_t)N_NODES * DDIM;     // NBATCH*DDIM
    float* HN  = EMB + (size_t)NBATCH * DDIM;      // NBATCH*HIDD
    float* H   = HN  + (size_t)NBATCH * HIDD;      // NBATCH*HIDD
    float* T   = H   + (size_t)NBATCH * HIDD;      // NBATCH*HEXP
    float* PP  = T   + (size_t)NBATCH * HEXP;      // NBATCH*NCLS*RNK

    const int* esrc = eidx;
    const int* edst = eidx + N_EDGES;

    const int node4 = N_NODES * DDIM / 4;
    dim3 blk(256);

    // ---- GNN tail ----
    copy4_kernel<<<dim3((node4 + 255) / 256), blk, 0, stream>>>((float4*)X, (const float4*)fro, node4);

    const float* Ws[2] = {W6, W7};
    const float* bs[2] = {b6, b7};
    for (int l = 0; l < 2; ++l) {
        dim3 g1((DDIM + 127) / 128, (N_NODES + 127) / 128);
        gemm_f32<0, false><<<g1, blk, 0, stream>>>(X, DDIM, Ws[l], DDIM, Y, DDIM, nullptr,
                                                   N_NODES, DDIM, DDIM);
        zero4_kernel<<<dim3((node4 + 255) / 256), blk, 0, stream>>>((float4*)AGG, node4);
        edge_scatter_kernel<<<dim3((int)(((long long)N_EDGES * 64 + 255) / 256)), blk, 0, stream>>>(
            Y, esrc, edst, ew, AGG);
        node_update_kernel<<<dim3((node4 + 255) / 256), blk, 0, stream>>>(X, AGG, bs[l]);
    }
    // post_mp projection: Z (stored in Y) = X @ Wp + bp
    {
        dim3 g1((DDIM + 127) / 128, (N_NODES + 127) / 128);
        gemm_f32<0, false><<<g1, blk, 0, stream>>>(X, DDIM, Wp, DDIM, Y, DDIM, bp,
                                                   N_NODES, DDIM, DDIM);
    }
    // gather with OOV
    gather_emb_kernel<<<dim3(NBATCH), blk, 0, stream>>>(Y, idxs, oov, EMB);

    // ---- head ----
    ln_kernel<<<dim3(NBATCH), blk, 0, stream>>>(EMB, in_g, in_b, HN, DDIM);
    {
        dim3 g((HIDD + 127) / 128, (NBATCH + 127) / 128);
        gemm_f32<0, false><<<g, blk, 0, stream>>>(HN, DDIM, inW, HIDD, H, HIDD, inb,
                                                  NBATCH, HIDD, DDIM);
    }
    for (int i = 0; i < NBLK; ++i) {
        ln_kernel<<<dim3(NBATCH), blk, 0, stream>>>(H, bg + (size_t)i * HIDD, bb + (size_t)i * HIDD,
                                                    HN, HIDD);
        dim3 g1((HEXP + 127) / 128, (NBATCH + 127) / 128);
        gemm_f32<2, false><<<g1, blk, 0, stream>>>(HN, HIDD, f1W + (size_t)i * HIDD * HEXP, HEXP,
                                                   T, HEXP, f1b + (size_t)i * HEXP,
                                                   NBATCH, HEXP, HIDD);
        dim3 g2((HIDD + 127) / 128, (NBATCH + 127) / 128);
        gemm_f32<3, false><<<g2, blk, 0, stream>>>(T, HEXP, f2W + (size_t)i * HEXP * HIDD, HIDD,
                                                   H, HIDD, f2b + (size_t)i * HIDD,
                                                   NBATCH, HIDD, HEXP);
    }
    ln_kernel<<<dim3(NBATCH), blk, 0, stream>>>(H, og, ob, HN, HIDD);
    {
        dim3 g((NCLS * RNK + 127) / 128, (NBATCH + 127) / 128);
        gemm_f32<0, false><<<g, blk, 0, stream>>>(HN, HIDD, oW, NCLS * RNK, PP, NCLS * RNK, obia,
                                                  NBATCH, NCLS * RNK, HIDD);
    }
    // bilinear gene head: 3 GEMMs against gene_emb^T
    for (int c = 0; c < NCLS; ++c) {
        dim3 g((NGENE + 127) / 128, (NBATCH + 127) / 128);
        gemm_f32<0, true><<<g, blk, 0, stream>>>(PP + (size_t)c * RNK, NCLS * RNK,
                                                 gene, RNK,
                                                 out + (size_t)c * NGENE, NCLS * NGENE, nullptr,
                                                 NBATCH, NGENE, RNK);
    }
}

// Round 2
// 1953.471 us; speedup vs baseline: 4.4278x; 4.4278x over previous
//
#include <hip/hip_runtime.h>
#include <cstdint>
#include <cstddef>

#define N_NODES 20000
#define N_EDGES 640000
#define DDIM    256
#define HIDD    512
#define NBLK    6
#define HEXP    2048   // HID*EXP
#define NCLS    3
#define RNK     512
#define NGENE   6640
#define NBATCH  4096

typedef __attribute__((ext_vector_type(8))) short short8;
typedef __attribute__((ext_vector_type(4))) float f32x4;

__device__ __forceinline__ float gelu_tanh(float x) {
    float x3 = x * x * x;
    return 0.5f * x * (1.f + tanhf(0.7978845608028654f * (x + 0.044715f * x3)));
}

// f32 -> bf16 RNE bit pattern
__device__ __forceinline__ unsigned short f2bf(float f) {
    unsigned u = __float_as_uint(f);
    unsigned r = (u + 0x7FFFu + ((u >> 16) & 1u)) >> 16;
    return (unsigned short)r;
}

// ---------------- utility kernels ----------------
__global__ __launch_bounds__(256) void copy4_kernel(float4* __restrict__ dst,
                                                    const float4* __restrict__ src, int n4) {
    int i = blockIdx.x * 256 + threadIdx.x;
    if (i < n4) dst[i] = src[i];
}

__global__ __launch_bounds__(256) void zero_int_kernel(int* __restrict__ p, int n) {
    int i = blockIdx.x * 256 + threadIdx.x;
    if (i < n) p[i] = 0;
}

// f32 -> bf16, 4 elements per thread (n must be multiple of 4)
__global__ __launch_bounds__(256) void conv_bf16_kernel(const float* __restrict__ in,
                                                        unsigned short* __restrict__ out, int n4) {
    int i = blockIdx.x * 256 + threadIdx.x;
    if (i >= n4) return;
    float4 v = ((const float4*)in)[i];
    ushort4 o;
    o.x = f2bf(v.x); o.y = f2bf(v.y); o.z = f2bf(v.z); o.w = f2bf(v.w);
    ((ushort4*)out)[i] = o;
}

// transpose + convert: in f32 [R][C] -> out bf16 [C][R]
__global__ __launch_bounds__(256) void tconv_kernel(const float* __restrict__ in,
                                                    unsigned short* __restrict__ out,
                                                    int R, int C) {
    __shared__ float tile[32][33];
    int c0 = blockIdx.x * 32, r0 = blockIdx.y * 32;
    int tx = threadIdx.x & 31, ty = threadIdx.x >> 5;   // 32 x 8
#pragma unroll
    for (int i = 0; i < 4; ++i) {
        int r = r0 + ty + i * 8, c = c0 + tx;
        tile[ty + i * 8][tx] = (r < R && c < C) ? in[(size_t)r * C + c] : 0.f;
    }
    __syncthreads();
#pragma unroll
    for (int i = 0; i < 4; ++i) {
        int c = c0 + ty + i * 8, r = r0 + tx;
        if (c < C && r < R) out[(size_t)c * R + r] = f2bf(tile[tx][ty + i * 8]);
    }
}

// ---------------- CSR build ----------------
__global__ __launch_bounds__(256) void hist_kernel(const int* __restrict__ dst,
                                                   int* __restrict__ cnt) {
    int e = blockIdx.x * 256 + threadIdx.x;
    if (e < N_EDGES) atomicAdd(&cnt[dst[e]], 1);
}

// single block 256 threads: exclusive scan of cnt[0..N_NODES) -> off, also copy to cur
__global__ __launch_bounds__(256) void scan_kernel(const int* __restrict__ cnt,
                                                   int* __restrict__ off,
                                                   int* __restrict__ cur) {
    __shared__ int part[256];
    const int CH = (N_NODES + 255) / 256;  // 79
    int t = threadIdx.x;
    int base = t * CH;
    int s = 0;
    for (int j = 0; j < CH; ++j) {
        int i = base + j;
        if (i < N_NODES) s += cnt[i];
    }
    part[t] = s;
    __syncthreads();
    for (int d = 1; d < 256; d <<= 1) {
        int v = (t >= d) ? part[t - d] : 0;
        __syncthreads();
        part[t] += v;
        __syncthreads();
    }
    int run = part[t] - s;  // exclusive prefix of this chunk
    for (int j = 0; j < CH; ++j) {
        int i = base + j;
        if (i < N_NODES) {
            off[i] = run; cur[i] = run;
            run += cnt[i];
        }
    }
    if (t == 255) off[N_NODES] = run;
}

__global__ __launch_bounds__(256) void fill_kernel(const int* __restrict__ src,
                                                   const int* __restrict__ dst,
                                                   const float* __restrict__ ew,
                                                   int* __restrict__ cur,
                                                   int* __restrict__ ssrc,
                                                   float* __restrict__ sw) {
    int e = blockIdx.x * 256 + threadIdx.x;
    if (e >= N_EDGES) return;
    int slot = atomicAdd(&cur[dst[e]], 1);
    ssrc[slot] = src[e];
    sw[slot]   = ew[e];
}

// fused aggregation + update: X[n][t] += relu(sum_j Y[src_j][t]*w_j + bias[t])
__global__ __launch_bounds__(256) void agg_update_kernel(const float* __restrict__ Y,
                                                         const int* __restrict__ off,
                                                         const int* __restrict__ ssrc,
                                                         const float* __restrict__ sw,
                                                         const float* __restrict__ bias,
                                                         float* __restrict__ X) {
    int n = blockIdx.x, t = threadIdx.x;
    int b = off[n], e = off[n + 1];
    float acc = 0.f;
    for (int j = b; j < e; ++j) {
        int s = ssrc[j];
        float w = sw[j];
        acc += Y[(size_t)s * DDIM + t] * w;
    }
    size_t o = (size_t)n * DDIM + t;
    X[o] += fmaxf(acc + bias[t], 0.f);
}

// EMB[b][t] = idx[b] >= 0 ? Z[idx[b]][t] : oov[t]
__global__ __launch_bounds__(256) void gather_emb_kernel(const float* __restrict__ Z,
                                                         const int* __restrict__ idxs,
                                                         const float* __restrict__ oov,
                                                         float* __restrict__ EMB) {
    int b = blockIdx.x, t = threadIdx.x;
    int id = idxs[b];
    EMB[(size_t)b * DDIM + t] = (id >= 0) ? Z[(size_t)id * DDIM + t] : oov[t];
}

// LayerNorm, f32 in -> bf16 out. one block per row.
__global__ __launch_bounds__(256) void ln_kernel(const float* __restrict__ X,
                                                 const float* __restrict__ g,
                                                 const float* __restrict__ bb,
                                                 unsigned short* __restrict__ Y, int ncol) {
    __shared__ float s1[256];
    __shared__ float s2[256];
    int row = blockIdx.x, t = threadIdx.x;
    const float* x = X + (size_t)row * ncol;
    float sum = 0.f, sq = 0.f;
    for (int c = t; c < ncol; c += 256) {
        float v = x[c];
        sum += v; sq += v * v;
    }
    s1[t] = sum; s2[t] = sq;
    __syncthreads();
    for (int o = 128; o > 0; o >>= 1) {
        if (t < o) { s1[t] += s1[t + o]; s2[t] += s2[t + o]; }
        __syncthreads();
    }
    float inv = 1.f / (float)ncol;
    float mu  = s1[0] * inv;
    float var = s2[0] * inv - mu * mu;
    float r   = rsqrtf(var + 1e-5f);
    unsigned short* y = Y + (size_t)row * ncol;
    for (int c = t; c < ncol; c += 256) {
        y[c] = f2bf((x[c] - mu) * r * g[c] + bb[c]);
    }
}

// ---------------- bf16 MFMA GEMM ----------------
// C[M,N] = epi(A[M,K]bf16 @ BT[N,K]bf16^T + bias)
// 128x128 tile, BK=64, 256 threads = 4 waves (2x2), each wave 64x64 (4x4 frags of 16x16x32)
// EPI: 0 = +bias ; 2 = gelu(+bias) ; 3 = C(f32) += (+bias)
// BOUT: write bf16 (ushort) instead of f32
template <int EPI, bool BOUT>
__global__ __launch_bounds__(256) void gemm_mfma(const unsigned short* __restrict__ A, int lda,
                                                 const unsigned short* __restrict__ BT, int ldb,
                                                 void* __restrict__ Cv, int ldc,
                                                 const float* __restrict__ bias,
                                                 int M, int N, int K) {
    __shared__ __align__(16) short lds[2 * 128 * 64];
    short* ldsA = lds;
    short* ldsB = lds + 128 * 64;

    const int tid  = threadIdx.x;
    const int lane = tid & 63;
    const int wid  = tid >> 6;
    const int wr   = (wid >> 1) * 64;   // wave row offset in tile
    const int wc   = (wid & 1) * 64;    // wave col offset in tile
    const int fq   = lane >> 4;         // 0..3
    const int fr   = lane & 15;         // 0..15
    const int m0 = blockIdx.y * 128, n0 = blockIdx.x * 128;
    const int srow0 = tid >> 3;         // 0..31
    const int sslot = tid & 7;          // 0..7 (16B slot within 128B row)

    f32x4 acc[4][4] = {};

    for (int k0 = 0; k0 < K; k0 += 64) {
        __syncthreads();
        // ---- stage A [128][64] bf16, swizzled 16B slots ----
#pragma unroll
        for (int p = 0; p < 4; ++p) {
            int row = p * 32 + srow0;
            int gr  = m0 + row;
            uint4 v = make_uint4(0, 0, 0, 0);
            if (gr < M) v = *(const uint4*)(A + (size_t)gr * lda + k0 + sslot * 8);
            *(uint4*)((char*)ldsA + row * 128 + ((sslot ^ (row & 7)) << 4)) = v;
        }
        // ---- stage BT [128][64] bf16 ----
#pragma unroll
        for (int p = 0; p < 4; ++p) {
            int row = p * 32 + srow0;
            int gr  = n0 + row;
            uint4 v = make_uint4(0, 0, 0, 0);
            if (gr < N) v = *(const uint4*)(BT + (size_t)gr * ldb + k0 + sslot * 8);
            *(uint4*)((char*)ldsB + row * 128 + ((sslot ^ (row & 7)) << 4)) = v;
        }
        __syncthreads();
        // ---- compute ----
#pragma unroll
        for (int kk = 0; kk < 2; ++kk) {
            short8 af[4], bf[4];
#pragma unroll
            for (int m = 0; m < 4; ++m) {
                int row  = wr + m * 16 + fr;
                int slot = kk * 4 + fq;
                af[m] = *(const short8*)((const char*)ldsA + row * 128 + ((slot ^ (row & 7)) << 4));
            }
#pragma unroll
            for (int n = 0; n < 4; ++n) {
                int row  = wc + n * 16 + fr;
                int slot = kk * 4 + fq;
                bf[n] = *(const short8*)((const char*)ldsB + row * 128 + ((slot ^ (row & 7)) << 4));
            }
#pragma unroll
            for (int m = 0; m < 4; ++m)
#pragma unroll
                for (int n = 0; n < 4; ++n)
                    acc[m][n] = __builtin_amdgcn_mfma_f32_16x16x32_bf16(af[m], bf[n], acc[m][n], 0, 0, 0);
        }
    }

    // ---- epilogue ----
    float* Cf = (float*)Cv;
    unsigned short* Cb = (unsigned short*)Cv;
#pragma unroll
    for (int n = 0; n < 4; ++n) {
        int col = n0 + wc + n * 16 + fr;
        if (col >= N) continue;
        float bv = bias ? bias[col] : 0.f;
#pragma unroll
        for (int m = 0; m < 4; ++m) {
#pragma unroll
            for (int r = 0; r < 4; ++r) {
                int row = m0 + wr + m * 16 + fq * 4 + r;
                if (row >= M) continue;
                float v = acc[m][n][r] + bv;
                if (EPI == 2) v = gelu_tanh(v);
                size_t o = (size_t)row * ldc + col;
                if (EPI == 3) v += Cf[o];
                if (BOUT) Cb[o] = f2bf(v);
                else      Cf[o] = v;
            }
        }
    }
}

// ---------------- launcher ----------------
static inline char* align256(char* p) {
    return (char*)(((uintptr_t)p + 255) & ~(uintptr_t)255);
}

extern "C" void kernel_launch(void* const* d_in, const int* in_sizes, int n_in,
                              void* d_out, int out_size, void* d_ws, size_t ws_size,
                              hipStream_t stream) {
    const int*   idxs = (const int*)d_in[0];
    const float* fro  = (const float*)d_in[1];
    const int*   eidx = (const int*)d_in[2];
    const float* ew   = (const float*)d_in[3];
    const float* W6   = (const float*)d_in[4];
    const float* b6   = (const float*)d_in[5];
    const float* W7   = (const float*)d_in[6];
    const float* b7   = (const float*)d_in[7];
    const float* Wp   = (const float*)d_in[8];
    const float* bp   = (const float*)d_in[9];
    const float* oov  = (const float*)d_in[10];
    const float* in_g = (const float*)d_in[11];
    const float* in_b = (const float*)d_in[12];
    const float* inW  = (const float*)d_in[13];
    const float* inb  = (const float*)d_in[14];
    const float* bg   = (const float*)d_in[15];
    const float* bb   = (const float*)d_in[16];
    const float* f1W  = (const float*)d_in[17];
    const float* f1b  = (const float*)d_in[18];
    const float* f2W  = (const float*)d_in[19];
    const float* f2b  = (const float*)d_in[20];
    const float* og   = (const float*)d_in[21];
    const float* ob   = (const float*)d_in[22];
    const float* oW   = (const float*)d_in[23];
    const float* obia = (const float*)d_in[24];
    const float* gene = (const float*)d_in[25];
    float* out = (float*)d_out;

    // ---- workspace carve-up ----
    char* p = (char*)d_ws;
    auto alloc_f = [&](size_t n) { float* r = (float*)p; p = align256(p + n * 4); return r; };
    auto alloc_i = [&](size_t n) { int*   r = (int*)p;   p = align256(p + n * 4); return r; };
    auto alloc_h = [&](size_t n) { unsigned short* r = (unsigned short*)p; p = align256(p + n * 2); return r; };

    float* X    = alloc_f((size_t)N_NODES * DDIM);
    float* Y    = alloc_f((size_t)N_NODES * DDIM);
    int*   cnt  = alloc_i(N_NODES);
    int*   off  = alloc_i(N_NODES + 1);
    int*   cur  = alloc_i(N_NODES);
    int*   ssrc = alloc_i(N_EDGES);
    float* sw   = alloc_f(N_EDGES);
    unsigned short* Xb  = alloc_h((size_t)N_NODES * DDIM);
    float* EMB  = alloc_f((size_t)NBATCH * DDIM);
    unsigned short* HNb = alloc_h((size_t)NBATCH * HIDD);
    float* H    = alloc_f((size_t)NBATCH * HIDD);
    unsigned short* Tb  = alloc_h((size_t)NBATCH * HEXP);
    unsigned short* PPb = alloc_h((size_t)NBATCH * NCLS * RNK);
    unsigned short* W6T  = alloc_h((size_t)DDIM * DDIM);
    unsigned short* W7T  = alloc_h((size_t)DDIM * DDIM);
    unsigned short* WpT  = alloc_h((size_t)DDIM * DDIM);
    unsigned short* inWT = alloc_h((size_t)DDIM * HIDD);
    unsigned short* f1WT = alloc_h((size_t)NBLK * HIDD * HEXP);
    unsigned short* f2WT = alloc_h((size_t)NBLK * HIDD * HEXP);
    unsigned short* oWT  = alloc_h((size_t)HIDD * NCLS * RNK);
    unsigned short* geneB= alloc_h((size_t)NGENE * RNK);

    const int* esrc = eidx;
    const int* edst = eidx + N_EDGES;
    dim3 blk(256);

    // ---- weight prep: transpose+convert to bf16 [N][K] ----
    tconv_kernel<<<dim3(8, 8),   blk, 0, stream>>>(W6, W6T, DDIM, DDIM);
    tconv_kernel<<<dim3(8, 8),   blk, 0, stream>>>(W7, W7T, DDIM, DDIM);
    tconv_kernel<<<dim3(8, 8),   blk, 0, stream>>>(Wp, WpT, DDIM, DDIM);
    tconv_kernel<<<dim3(16, 8),  blk, 0, stream>>>(inW, inWT, DDIM, HIDD);
    for (int i = 0; i < NBLK; ++i) {
        tconv_kernel<<<dim3(64, 16), blk, 0, stream>>>(f1W + (size_t)i * HIDD * HEXP,
                                                       f1WT + (size_t)i * HEXP * HIDD, HIDD, HEXP);
        tconv_kernel<<<dim3(16, 64), blk, 0, stream>>>(f2W + (size_t)i * HEXP * HIDD,
                                                       f2WT + (size_t)i * HIDD * HEXP, HEXP, HIDD);
    }
    tconv_kernel<<<dim3(48, 16), blk, 0, stream>>>(oW, oWT, HIDD, NCLS * RNK);
    conv_bf16_kernel<<<dim3((NGENE * RNK / 4 + 255) / 256), blk, 0, stream>>>(gene, geneB, NGENE * RNK / 4);

    // ---- CSR build (by dst) ----
    zero_int_kernel<<<dim3((N_NODES + 255) / 256), blk, 0, stream>>>(cnt, N_NODES);
    hist_kernel<<<dim3(N_EDGES / 256), blk, 0, stream>>>(edst, cnt);
    scan_kernel<<<dim3(1), blk, 0, stream>>>(cnt, off, cur);
    fill_kernel<<<dim3(N_EDGES / 256), blk, 0, stream>>>(esrc, edst, ew, cur, ssrc, sw);

    // ---- GNN tail ----
    const int node4 = N_NODES * DDIM / 4;
    copy4_kernel<<<dim3((node4 + 255) / 256), blk, 0, stream>>>((float4*)X, (const float4*)fro, node4);

    const unsigned short* WTs[2] = {W6T, W7T};
    const float* bs[2] = {b6, b7};
    dim3 gnn_grid((DDIM + 127) / 128, (N_NODES + 127) / 128);
    for (int l = 0; l < 2; ++l) {
        conv_bf16_kernel<<<dim3((node4 + 255) / 256), blk, 0, stream>>>(X, Xb, node4);
        gemm_mfma<0, false><<<gnn_grid, blk, 0, stream>>>(Xb, DDIM, WTs[l], DDIM, Y, DDIM,
                                                          nullptr, N_NODES, DDIM, DDIM);
        agg_update_kernel<<<dim3(N_NODES), blk, 0, stream>>>(Y, off, ssrc, sw, bs[l], X);
    }
    // post_mp projection: Y = X @ Wp + bp
    conv_bf16_kernel<<<dim3((node4 + 255) / 256), blk, 0, stream>>>(X, Xb, node4);
    gemm_mfma<0, false><<<gnn_grid, blk, 0, stream>>>(Xb, DDIM, WpT, DDIM, Y, DDIM,
                                                      bp, N_NODES, DDIM, DDIM);
    // gather with OOV
    gather_emb_kernel<<<dim3(NBATCH), blk, 0, stream>>>(Y, idxs, oov, EMB);

    // ---- head ----
    ln_kernel<<<dim3(NBATCH), blk, 0, stream>>>(EMB, in_g, in_b, HNb, DDIM);
    gemm_mfma<0, false><<<dim3(HIDD / 128, NBATCH / 128), blk, 0, stream>>>(
        HNb, DDIM, inWT, DDIM, H, HIDD, inb, NBATCH, HIDD, DDIM);
    for (int i = 0; i < NBLK; ++i) {
        ln_kernel<<<dim3(NBATCH), blk, 0, stream>>>(H, bg + (size_t)i * HIDD,
                                                    bb + (size_t)i * HIDD, HNb, HIDD);
        gemm_mfma<2, true><<<dim3(HEXP / 128, NBATCH / 128), blk, 0, stream>>>(
            HNb, HIDD, f1WT + (size_t)i * HEXP * HIDD, HIDD, Tb, HEXP,
            f1b + (size_t)i * HEXP, NBATCH, HEXP, HIDD);
        gemm_mfma<3, false><<<dim3(HIDD / 128, NBATCH / 128), blk, 0, stream>>>(
            Tb, HEXP, f2WT + (size_t)i * HIDD * HEXP, HEXP, H, HIDD,
            f2b + (size_t)i * HIDD, NBATCH, HIDD, HEXP);
    }
    ln_kernel<<<dim3(NBATCH), blk, 0, stream>>>(H, og, ob, HNb, HIDD);
    gemm_mfma<0, true><<<dim3(NCLS * RNK / 128, NBATCH / 128), blk, 0, stream>>>(
        HNb, HIDD, oWT, HIDD, PPb, NCLS * RNK, obia, NBATCH, NCLS * RNK, HIDD);

    // ---- bilinear gene head: logits[b][c][g] ----
    for (int c = 0; c < NCLS; ++c) {
        gemm_mfma<0, false><<<dim3((NGENE + 127) / 128, NBATCH / 128), blk, 0, stream>>>(
            PPb + (size_t)c * RNK, NCLS * RNK, geneB, RNK,
            out + (size_t)c * NGENE, NCLS * NGENE, nullptr, NBATCH, NGENE, RNK);
    }
}

// Round 3
// 1121.316 us; speedup vs baseline: 7.7138x; 1.7421x over previous
//
#include <hip/hip_runtime.h>
#include <cstdint>
#include <cstddef>

#define N_NODES 20000
#define N_PAD   20096   // 157*128
#define N_EDGES 640000
#define DDIM    256
#define HIDD    512
#define NBLK    6
#define HEXP    2048    // HID*EXP
#define NCLS    3
#define RNK     512
#define NGENE   6640
#define NGPAD   6656    // 52*128
#define NBATCH  4096

typedef __attribute__((ext_vector_type(8))) short short8;
typedef __attribute__((ext_vector_type(4))) float f32x4;

__device__ __forceinline__ float gelu_tanh(float x) {
    float x3 = x * x * x;
    return 0.5f * x * (1.f + tanhf(0.7978845608028654f * (x + 0.044715f * x3)));
}

// f32 -> bf16 RNE bit pattern
__device__ __forceinline__ unsigned short f2bf(float f) {
    unsigned u = __float_as_uint(f);
    unsigned r = (u + 0x7FFFu + ((u >> 16) & 1u)) >> 16;
    return (unsigned short)r;
}

// async global->LDS, 16B per lane. LDS dest is wave-uniform base + lane*16.
__device__ __forceinline__ void gload16(const unsigned short* g, short* l) {
    __builtin_amdgcn_global_load_lds(
        (const __attribute__((address_space(1))) void*)g,
        (__attribute__((address_space(3))) void*)l, 16, 0, 0);
}

// ---------------- utility kernels ----------------
// X (f32 copy) and Xb (bf16) from frozen states
__global__ __launch_bounds__(256) void initX_kernel(const float4* __restrict__ fro,
                                                    float4* __restrict__ X,
                                                    ushort4* __restrict__ Xb, int n4) {
    int i = blockIdx.x * 256 + threadIdx.x;
    if (i >= n4) return;
    float4 v = fro[i];
    X[i] = v;
    ushort4 h;
    h.x = f2bf(v.x); h.y = f2bf(v.y); h.z = f2bf(v.z); h.w = f2bf(v.w);
    Xb[i] = h;
}

__global__ __launch_bounds__(256) void zero_int_kernel(int* __restrict__ p, int n) {
    int i = blockIdx.x * 256 + threadIdx.x;
    if (i < n) p[i] = 0;
}

// f32 -> bf16, 4 elements per thread
__global__ __launch_bounds__(256) void conv_bf16_kernel(const float* __restrict__ in,
                                                        unsigned short* __restrict__ out, int n4) {
    int i = blockIdx.x * 256 + threadIdx.x;
    if (i >= n4) return;
    float4 v = ((const float4*)in)[i];
    ushort4 o;
    o.x = f2bf(v.x); o.y = f2bf(v.y); o.z = f2bf(v.z); o.w = f2bf(v.w);
    ((ushort4*)out)[i] = o;
}

// transpose + convert: in f32 [R][C] -> out bf16 [C][R]; blockIdx.z batches
__global__ __launch_bounds__(256) void tconv_kernel(const float* __restrict__ in,
                                                    unsigned short* __restrict__ out,
                                                    int R, int C) {
    __shared__ float tile[32][33];
    size_t zo = (size_t)blockIdx.z * R * C;
    in += zo; out += zo;
    int c0 = blockIdx.x * 32, r0 = blockIdx.y * 32;
    int tx = threadIdx.x & 31, ty = threadIdx.x >> 5;   // 32 x 8
#pragma unroll
    for (int i = 0; i < 4; ++i) {
        int r = r0 + ty + i * 8, c = c0 + tx;
        tile[ty + i * 8][tx] = (r < R && c < C) ? in[(size_t)r * C + c] : 0.f;
    }
    __syncthreads();
#pragma unroll
    for (int i = 0; i < 4; ++i) {
        int c = c0 + ty + i * 8, r = r0 + tx;
        if (c < C && r < R) out[(size_t)c * R + r] = f2bf(tile[tx][ty + i * 8]);
    }
}

// ---------------- CSR build ----------------
__global__ __launch_bounds__(256) void hist_kernel(const int* __restrict__ dst,
                                                   int* __restrict__ cnt) {
    int e = blockIdx.x * 256 + threadIdx.x;
    if (e < N_EDGES) atomicAdd(&cnt[dst[e]], 1);
}

__global__ __launch_bounds__(256) void scan_kernel(const int* __restrict__ cnt,
                                                   int* __restrict__ off,
                                                   int* __restrict__ cur) {
    __shared__ int part[256];
    const int CH = (N_NODES + 255) / 256;
    int t = threadIdx.x;
    int base = t * CH;
    int s = 0;
    for (int j = 0; j < CH; ++j) {
        int i = base + j;
        if (i < N_NODES) s += cnt[i];
    }
    part[t] = s;
    __syncthreads();
    for (int d = 1; d < 256; d <<= 1) {
        int v = (t >= d) ? part[t - d] : 0;
        __syncthreads();
        part[t] += v;
        __syncthreads();
    }
    int run = part[t] - s;
    for (int j = 0; j < CH; ++j) {
        int i = base + j;
        if (i < N_NODES) {
            off[i] = run; cur[i] = run;
            run += cnt[i];
        }
    }
    if (t == 255) off[N_NODES] = run;
}

__global__ __launch_bounds__(256) void fill_kernel(const int* __restrict__ src,
                                                   const int* __restrict__ dst,
                                                   const float* __restrict__ ew,
                                                   int* __restrict__ cur,
                                                   int* __restrict__ ssrc,
                                                   float* __restrict__ sw) {
    int e = blockIdx.x * 256 + threadIdx.x;
    if (e >= N_EDGES) return;
    int slot = atomicAdd(&cur[dst[e]], 1);
    ssrc[slot] = src[e];
    sw[slot]   = ew[e];
}

// fused aggregation + update, one wave per node, float4 per lane:
// X[n] += relu(sum_j Y[src_j]*w_j + bias); optionally also write bf16 copy
template <bool WB>
__global__ __launch_bounds__(256) void agg_update_kernel(const float* __restrict__ Y,
                                                         const int* __restrict__ off,
                                                         const int* __restrict__ ssrc,
                                                         const float* __restrict__ sw,
                                                         const float* __restrict__ bias,
                                                         float* __restrict__ X,
                                                         unsigned short* __restrict__ Xb) {
    int node = blockIdx.x * 4 + (threadIdx.x >> 6);
    int lane = threadIdx.x & 63;
    int b = off[node], e = off[node + 1];
    const float4* Yv = (const float4*)Y;
    float4 acc = make_float4(0.f, 0.f, 0.f, 0.f);
    for (int j = b; j < e; ++j) {
        int s = ssrc[j];
        float w = sw[j];
        float4 v = Yv[(size_t)s * 64 + lane];
        acc.x += v.x * w; acc.y += v.y * w; acc.z += v.z * w; acc.w += v.w * w;
    }
    float4 bv = ((const float4*)bias)[lane];
    size_t o = (size_t)node * 64 + lane;
    float4 x = ((float4*)X)[o];
    x.x += fmaxf(acc.x + bv.x, 0.f);
    x.y += fmaxf(acc.y + bv.y, 0.f);
    x.z += fmaxf(acc.z + bv.z, 0.f);
    x.w += fmaxf(acc.w + bv.w, 0.f);
    ((float4*)X)[o] = x;
    if (WB) {
        ushort4 h;
        h.x = f2bf(x.x); h.y = f2bf(x.y); h.z = f2bf(x.z); h.w = f2bf(x.w);
        ((ushort4*)Xb)[o] = h;
    }
}

// gather rows of X (f32) at clip(idx,0) -> bf16 [NBATCH][DDIM]
__global__ __launch_bounds__(256) void gather_cvt_kernel(const float* __restrict__ X,
                                                         const int* __restrict__ idxs,
                                                         unsigned short* __restrict__ Ag) {
    int b = blockIdx.x, t = threadIdx.x;
    int id = idxs[b];
    if (id < 0) id = 0;
    Ag[(size_t)b * DDIM + t] = f2bf(X[(size_t)id * DDIM + t]);
}

// LN over 256 cols with OOV row substitution, bf16 out. one block per row.
__global__ __launch_bounds__(256) void ln_oov_kernel(const float* __restrict__ Z,
                                                     const int* __restrict__ idxs,
                                                     const float* __restrict__ oov,
                                                     const float* __restrict__ g,
                                                     const float* __restrict__ bb,
                                                     unsigned short* __restrict__ Y) {
    __shared__ float s1[256];
    __shared__ float s2[256];
    int row = blockIdx.x, t = threadIdx.x;
    int id = idxs[row];
    float v = (id >= 0) ? Z[(size_t)row * DDIM + t] : oov[t];
    s1[t] = v; s2[t] = v * v;
    __syncthreads();
    for (int o = 128; o > 0; o >>= 1) {
        if (t < o) { s1[t] += s1[t + o]; s2[t] += s2[t + o]; }
        __syncthreads();
    }
    float mu  = s1[0] * (1.f / DDIM);
    float var = s2[0] * (1.f / DDIM) - mu * mu;
    float r   = rsqrtf(var + 1e-5f);
    Y[(size_t)row * DDIM + t] = f2bf((v - mu) * r * g[t] + bb[t]);
}

// generic LN, f32 in -> bf16 out. one block per row.
__global__ __launch_bounds__(256) void ln_kernel(const float* __restrict__ X,
                                                 const float* __restrict__ g,
                                                 const float* __restrict__ bb,
                                                 unsigned short* __restrict__ Y, int ncol) {
    __shared__ float s1[256];
    __shared__ float s2[256];
    int row = blockIdx.x, t = threadIdx.x;
    const float* x = X + (size_t)row * ncol;
    float sum = 0.f, sq = 0.f;
    for (int c = t; c < ncol; c += 256) {
        float v = x[c];
        sum += v; sq += v * v;
    }
    s1[t] = sum; s2[t] = sq;
    __syncthreads();
    for (int o = 128; o > 0; o >>= 1) {
        if (t < o) { s1[t] += s1[t + o]; s2[t] += s2[t + o]; }
        __syncthreads();
    }
    float inv = 1.f / (float)ncol;
    float mu  = s1[0] * inv;
    float var = s2[0] * inv - mu * mu;
    float r   = rsqrtf(var + 1e-5f);
    unsigned short* y = Y + (size_t)row * ncol;
    for (int c = t; c < ncol; c += 256) {
        y[c] = f2bf((x[c] - mu) * r * g[c] + bb[c]);
    }
}

// ---------------- bf16 MFMA GEMM (global_load_lds staging) ----------------
// C[M,N] = epi(A[M,K]bf16 @ BT[N,K]bf16^T + bias)
// BK=64, 256 threads = 4 waves in 2x2, wave tile (BM/2)x(BN/2), 16x16x32 frags.
// A/B staged by global_load_lds 16B/lane into linear LDS; XOR slot-swizzle is
// applied by pre-swizzling the GLOBAL source slot (rule: both-sides-or-neither).
// Caller guarantees A has ceil(M/BM)*BM valid rows and BT ceil-N rows allocated.
// EPI: 0 = +bias ; 2 = gelu(+bias) ; 3 = C(f32) += (+bias).  BOUT: bf16 store.
template <int BM, int BN, int EPI, bool BOUT>
__global__ __launch_bounds__(256) void gemm_mfma(const unsigned short* __restrict__ A, int lda,
                                                 const unsigned short* __restrict__ BT, int ldb,
                                                 void* __restrict__ Cv, int ldc,
                                                 const float* __restrict__ bias,
                                                 int M, int N, int K) {
    constexpr int WM = BM / 2, WN = BN / 2;
    constexpr int MF = WM / 16, NF = WN / 16;
    constexpr int ROWS  = BM + BN;
    constexpr int NCALL = ROWS / 32;         // 8-row chunks per wave per k-step
    __shared__ __align__(16) short lds[ROWS * 64];

    const int tid  = threadIdx.x;
    const int lane = tid & 63;
    const int wid  = tid >> 6;
    const int wr   = (wid >> 1) * WM;
    const int wc   = (wid & 1) * WN;
    const int fq   = lane >> 4;
    const int fr   = lane & 15;
    const int m0 = blockIdx.y * BM, n0 = blockIdx.x * BN;

    const int srow  = lane >> 3;                   // row within 8-row chunk
    const int tslot = ((lane & 7) ^ srow) * 8;     // pre-swizzled global slot (elems)

    f32x4 acc[MF][NF] = {};

    for (int k0 = 0; k0 < K; k0 += 64) {
        __syncthreads();
#pragma unroll
        for (int c = 0; c < NCALL; ++c) {
            int r = c * 32 + wid * 8 + srow;       // concatenated row (A then B)
            const unsigned short* src =
                (r < BM) ? (A  + (size_t)(m0 + r) * lda      + k0 + tslot)
                         : (BT + (size_t)(n0 + r - BM) * ldb + k0 + tslot);
            gload16(src, lds + (c * 32 + wid * 8) * 64);
        }
        __syncthreads();
#pragma unroll
        for (int kk = 0; kk < 2; ++kk) {
            short8 af[MF], bf[NF];
#pragma unroll
            for (int m = 0; m < MF; ++m) {
                int row = wr + m * 16 + fr;
                af[m] = *(const short8*)(lds + row * 64 + ((kk * 4 + fq) ^ (row & 7)) * 8);
            }
#pragma unroll
            for (int n = 0; n < NF; ++n) {
                int row = BM + wc + n * 16 + fr;
                bf[n] = *(const short8*)(lds + row * 64 + ((kk * 4 + fq) ^ (row & 7)) * 8);
            }
#pragma unroll
            for (int m = 0; m < MF; ++m)
#pragma unroll
                for (int n = 0; n < NF; ++n)
                    acc[m][n] = __builtin_amdgcn_mfma_f32_16x16x32_bf16(af[m], bf[n], acc[m][n], 0, 0, 0);
        }
    }

    float* Cf = (float*)Cv;
    unsigned short* Cb = (unsigned short*)Cv;
#pragma unroll
    for (int n = 0; n < NF; ++n) {
        int col = n0 + wc + n * 16 + fr;
        if (col >= N) continue;
        float bv = bias ? bias[col] : 0.f;
#pragma unroll
        for (int m = 0; m < MF; ++m) {
#pragma unroll
            for (int r = 0; r < 4; ++r) {
                int row = m0 + wr + m * 16 + fq * 4 + r;
                if (row >= M) continue;
                float v = acc[m][n][r] + bv;
                if (EPI == 2) v = gelu_tanh(v);
                size_t o = (size_t)row * ldc + col;
                if (EPI == 3) v += Cf[o];
                if (BOUT) Cb[o] = f2bf(v);
                else      Cf[o] = v;
            }
        }
    }
}

// ---------------- launcher ----------------
static inline char* align256(char* p) {
    return (char*)(((uintptr_t)p + 255) & ~(uintptr_t)255);
}

extern "C" void kernel_launch(void* const* d_in, const int* in_sizes, int n_in,
                              void* d_out, int out_size, void* d_ws, size_t ws_size,
                              hipStream_t stream) {
    const int*   idxs = (const int*)d_in[0];
    const float* fro  = (const float*)d_in[1];
    const int*   eidx = (const int*)d_in[2];
    const float* ew   = (const float*)d_in[3];
    const float* W6   = (const float*)d_in[4];
    const float* b6   = (const float*)d_in[5];
    const float* W7   = (const float*)d_in[6];
    const float* b7   = (const float*)d_in[7];
    const float* Wp   = (const float*)d_in[8];
    const float* bp   = (const float*)d_in[9];
    const float* oov  = (const float*)d_in[10];
    const float* in_g = (const float*)d_in[11];
    const float* in_b = (const float*)d_in[12];
    const float* inW  = (const float*)d_in[13];
    const float* inb  = (const float*)d_in[14];
    const float* bg   = (const float*)d_in[15];
    const float* bb   = (const float*)d_in[16];
    const float* f1W  = (const float*)d_in[17];
    const float* f1b  = (const float*)d_in[18];
    const float* f2W  = (const float*)d_in[19];
    const float* f2b  = (const float*)d_in[20];
    const float* og   = (const float*)d_in[21];
    const float* ob   = (const float*)d_in[22];
    const float* oW   = (const float*)d_in[23];
    const float* obia = (const float*)d_in[24];
    const float* gene = (const float*)d_in[25];
    float* out = (float*)d_out;

    // ---- workspace carve-up ----
    char* p = (char*)d_ws;
    auto alloc_f = [&](size_t n) { float* r = (float*)p; p = align256(p + n * 4); return r; };
    auto alloc_i = [&](size_t n) { int*   r = (int*)p;   p = align256(p + n * 4); return r; };
    auto alloc_h = [&](size_t n) { unsigned short* r = (unsigned short*)p; p = align256(p + n * 2); return r; };

    float* X    = alloc_f((size_t)N_NODES * DDIM);
    float* Y    = alloc_f((size_t)N_NODES * DDIM);
    int*   cnt  = alloc_i(N_NODES);
    int*   off  = alloc_i(N_NODES + 1);
    int*   cur  = alloc_i(N_NODES);
    int*   ssrc = alloc_i(N_EDGES);
    float* sw   = alloc_f(N_EDGES);
    unsigned short* Xb  = alloc_h((size_t)N_PAD * DDIM);      // padded rows for gload_lds
    unsigned short* Ag  = alloc_h((size_t)NBATCH * DDIM);
    float* Zp   = alloc_f((size_t)NBATCH * DDIM);
    unsigned short* HN256 = alloc_h((size_t)NBATCH * DDIM);
    float* H    = alloc_f((size_t)NBATCH * HIDD);
    unsigned short* HN512 = alloc_h((size_t)NBATCH * HIDD);
    unsigned short* Tb  = alloc_h((size_t)NBATCH * HEXP);
    unsigned short* PPb = alloc_h((size_t)NBATCH * NCLS * RNK);
    unsigned short* W6T  = alloc_h((size_t)DDIM * DDIM);
    unsigned short* W7T  = alloc_h((size_t)DDIM * DDIM);
    unsigned short* WpT  = alloc_h((size_t)DDIM * DDIM);
    unsigned short* inWT = alloc_h((size_t)HIDD * DDIM);
    unsigned short* f1WT = alloc_h((size_t)NBLK * HIDD * HEXP);
    unsigned short* f2WT = alloc_h((size_t)NBLK * HIDD * HEXP);
    unsigned short* oWT  = alloc_h((size_t)NCLS * RNK * HIDD);
    unsigned short* geneB= alloc_h((size_t)NGPAD * RNK);       // padded rows

    const int* esrc = eidx;
    const int* edst = eidx + N_EDGES;
    dim3 blk(256);

    // ---- weight prep: transpose+convert to bf16 [N][K] ----
    tconv_kernel<<<dim3(8, 8),       blk, 0, stream>>>(W6, W6T, DDIM, DDIM);
    tconv_kernel<<<dim3(8, 8),       blk, 0, stream>>>(W7, W7T, DDIM, DDIM);
    tconv_kernel<<<dim3(8, 8),       blk, 0, stream>>>(Wp, WpT, DDIM, DDIM);
    tconv_kernel<<<dim3(16, 8),      blk, 0, stream>>>(inW, inWT, DDIM, HIDD);
    tconv_kernel<<<dim3(64, 16, NBLK), blk, 0, stream>>>(f1W, f1WT, HIDD, HEXP);
    tconv_kernel<<<dim3(16, 64, NBLK), blk, 0, stream>>>(f2W, f2WT, HEXP, HIDD);
    tconv_kernel<<<dim3(48, 16),     blk, 0, stream>>>(oW, oWT, HIDD, NCLS * RNK);
    conv_bf16_kernel<<<dim3(NGENE * RNK / 4 / 256), blk, 0, stream>>>(gene, geneB, NGENE * RNK / 4);

    // ---- CSR build (by dst) ----
    zero_int_kernel<<<dim3((N_NODES + 255) / 256), blk, 0, stream>>>(cnt, N_NODES);
    hist_kernel<<<dim3(N_EDGES / 256), blk, 0, stream>>>(edst, cnt);
    scan_kernel<<<dim3(1), blk, 0, stream>>>(cnt, off, cur);
    fill_kernel<<<dim3(N_EDGES / 256), blk, 0, stream>>>(esrc, edst, ew, cur, ssrc, sw);

    // ---- GNN tail ----
    const int node4 = N_NODES * DDIM / 4;
    initX_kernel<<<dim3(node4 / 256), blk, 0, stream>>>((const float4*)fro, (float4*)X,
                                                        (ushort4*)Xb, node4);
    dim3 gnn_grid(DDIM / 128, N_PAD / 128);
    gemm_mfma<128, 128, 0, false><<<gnn_grid, blk, 0, stream>>>(
        Xb, DDIM, W6T, DDIM, Y, DDIM, nullptr, N_NODES, DDIM, DDIM);
    agg_update_kernel<true><<<dim3(N_NODES / 4), blk, 0, stream>>>(Y, off, ssrc, sw, b6, X, Xb);
    gemm_mfma<128, 128, 0, false><<<gnn_grid, blk, 0, stream>>>(
        Xb, DDIM, W7T, DDIM, Y, DDIM, nullptr, N_NODES, DDIM, DDIM);
    agg_update_kernel<false><<<dim3(N_NODES / 4), blk, 0, stream>>>(Y, off, ssrc, sw, b7, X, nullptr);

    // project only gathered rows: Ag = bf16(X[clip(idx)]), Zp = Ag @ Wp + bp
    gather_cvt_kernel<<<dim3(NBATCH), blk, 0, stream>>>(X, idxs, Ag);
    gemm_mfma<64, 128, 0, false><<<dim3(DDIM / 128, NBATCH / 64), blk, 0, stream>>>(
        Ag, DDIM, WpT, DDIM, Zp, DDIM, bp, NBATCH, DDIM, DDIM);
    // oov-select + input LN fused
    ln_oov_kernel<<<dim3(NBATCH), blk, 0, stream>>>(Zp, idxs, oov, in_g, in_b, HN256);

    // ---- head ----
    gemm_mfma<64, 128, 0, false><<<dim3(HIDD / 128, NBATCH / 64), blk, 0, stream>>>(
        HN256, DDIM, inWT, DDIM, H, HIDD, inb, NBATCH, HIDD, DDIM);
    for (int i = 0; i < NBLK; ++i) {
        ln_kernel<<<dim3(NBATCH), blk, 0, stream>>>(H, bg + (size_t)i * HIDD,
                                                    bb + (size_t)i * HIDD, HN512, HIDD);
        gemm_mfma<128, 128, 2, true><<<dim3(HEXP / 128, NBATCH / 128), blk, 0, stream>>>(
            HN512, HIDD, f1WT + (size_t)i * HEXP * HIDD, HIDD, Tb, HEXP,
            f1b + (size_t)i * HEXP, NBATCH, HEXP, HIDD);
        gemm_mfma<64, 128, 3, false><<<dim3(HIDD / 128, NBATCH / 64), blk, 0, stream>>>(
            Tb, HEXP, f2WT + (size_t)i * HIDD * HEXP, HEXP, H, HIDD,
            f2b + (size_t)i * HIDD, NBATCH, HIDD, HEXP);
    }
    ln_kernel<<<dim3(NBATCH), blk, 0, stream>>>(H, og, ob, HN512, HIDD);
    gemm_mfma<128, 128, 0, true><<<dim3(NCLS * RNK / 128, NBATCH / 128), blk, 0, stream>>>(
        HN512, HIDD, oWT, HIDD, PPb, NCLS * RNK, obia, NBATCH, NCLS * RNK, HIDD);

    // ---- bilinear gene head, fused over classes: rows (b,c) contiguous ----
    gemm_mfma<128, 128, 0, false><<<dim3(NGPAD / 128, NBATCH * NCLS / 128), blk, 0, stream>>>(
        PPb, RNK, geneB, RNK, out, NGENE, nullptr, NBATCH * NCLS, NGENE, RNK);
}